// Round 3
// baseline (2097.801 us; speedup 1.0000x reference)
//
#include <hip/hip_runtime.h>

// FeatureOctree, bucket-phased gather.
//
// Evidence so far: traffic is at the compulsory floor (~1.6 GB) and moves at
// ~3.2 TB/s (random-64B regime). The 4x average reuse of feature rows is lost
// because a row's ~4 references are spread over the whole kernel (~500 us)
// while LLC line survival under this miss rate is ~90 us (R1: 16% hit).
//
// This kernel clusters reuse in TIME: each thread holds 2 points' indices
// (48 ints), base coords, and accumulators (8 float4) in registers, then
// sweeps H=8 index-range buckets. In phase h the whole chip gathers only from
// a 48 MB table slice (3 levels x 16 MB), so a row's references land within
// one ~30 us phase and hit in the LLC. No idx re-reads (registers), no
// out-RMW (single launch), no grid sync (blocks start together and
// phase-align naturally; __syncthreads keeps waves aligned within a block).
//
// Bounded downside: if the LLC still refuses retention, fetch stays ~1.6 GB
// and we only pay the phase-loop VALU overhead (~5%).

typedef float v4f __attribute__((ext_vector_type(4)));
typedef int   v4i __attribute__((ext_vector_type(4)));

#define ACC_FMA(A, PK, G)                      \
    do {                                       \
        (A).x = fmaf((PK), (G).x, (A).x);      \
        (A).y = fmaf((PK), (G).y, (A).y);      \
        (A).z = fmaf((PK), (G).z, (A).z);      \
        (A).w = fmaf((PK), (G).w, (A).w);      \
    } while (0)

__global__ __launch_bounds__(256, 4) void FeatureOctree_74749610820348_kernel(
    const float* __restrict__ x,
    const v4f* __restrict__ f0,
    const v4f* __restrict__ f1,
    const v4f* __restrict__ f2,
    const int* __restrict__ i0,
    const int* __restrict__ i1,
    const int* __restrict__ i2,
    v4f* __restrict__ out,
    int n_pts, int shift, int nphase)
{
    long long tid = (long long)blockIdx.x * blockDim.x + threadIdx.x;
    long long pt0 = tid * 2;

    bool valid0 = (pt0     < n_pts);
    bool valid1 = (pt0 + 1 < n_pts);

    // ---- idx rows -> registers, held across all phases (48 ints) ----
    // Invalid points get id = -1; (-1 >> shift) == -1 never matches a phase.
    int id[2][3][8];
    const int* __restrict__ itab[3] = { i0, i1, i2 };
#pragma unroll
    for (int w = 0; w < 2; ++w) {
        bool v = w ? valid1 : valid0;
#pragma unroll
        for (int lv = 0; lv < 3; ++lv) {
            if (v) {
                const v4i* iv = (const v4i*)(itab[lv] + (pt0 + w) * 8);
                v4i ia = __builtin_nontemporal_load(iv);
                v4i ib = __builtin_nontemporal_load(iv + 1);
                id[w][lv][0] = ia.x; id[w][lv][1] = ia.y;
                id[w][lv][2] = ia.z; id[w][lv][3] = ia.w;
                id[w][lv][4] = ib.x; id[w][lv][5] = ib.y;
                id[w][lv][6] = ib.z; id[w][lv][7] = ib.w;
            } else {
#pragma unroll
                for (int k = 0; k < 8; ++k) id[w][lv][k] = -1;
            }
        }
    }

    // ---- x -> base coords in registers ----
    float bx[2], by[2], bz[2];
#pragma unroll
    for (int w = 0; w < 2; ++w) {
        bool v = w ? valid1 : valid0;
        float xv = 0.f, yv = 0.f, zv = 0.f;
        if (v) {
            xv = __builtin_nontemporal_load(x + (pt0 + w) * 3 + 0);
            yv = __builtin_nontemporal_load(x + (pt0 + w) * 3 + 1);
            zv = __builtin_nontemporal_load(x + (pt0 + w) * 3 + 2);
        }
        bx[w] = xv * 0.5f + 0.5f;
        by[w] = yv * 0.5f + 0.5f;
        bz[w] = zv * 0.5f + 0.5f;
    }

    v4f acc[2][4];
#pragma unroll
    for (int w = 0; w < 2; ++w)
#pragma unroll
        for (int q = 0; q < 4; ++q) acc[w][q] = (v4f){0.f, 0.f, 0.f, 0.f};

    const v4f* __restrict__ ftab[3] = { f0, f1, f2 };

    // ---- bucket-phase sweep ----
    for (int h = 0; h < nphase; ++h) {
#pragma unroll
        for (int w = 0; w < 2; ++w) {
#pragma unroll
            for (int lv = 0; lv < 3; ++lv) {
                const float scl = (lv == 0) ? 4096.0f : (lv == 1) ? 2048.0f : 1024.0f;
                float cx = scl * bx[w], cy = scl * by[w], cz = scl * bz[w];
                float dx = cx - floorf(cx);
                float dy = cy - floorf(cy);
                float dz = cz - floorf(cz);
                float tx = dx * dx * (3.0f - 2.0f * dx);
                float ty = dy * dy * (3.0f - 2.0f * dy);
                float tz = dz * dz * (3.0f - 2.0f * dz);
                float ux = 1.0f - tx, uy = 1.0f - ty, uz = 1.0f - tz;
#pragma unroll
                for (int k = 0; k < 8; ++k) {
                    int idk = id[w][lv][k];
                    if ((idk >> shift) == h) {
                        float pk = ((k & 4) ? tx : ux)
                                 * ((k & 2) ? ty : uy)
                                 * ((k & 1) ? tz : uz);
                        const v4f* row = ftab[lv] + (long long)idk * 4;
                        v4f g0 = row[0];
                        v4f g1 = row[1];
                        v4f g2 = row[2];
                        v4f g3 = row[3];
                        ACC_FMA(acc[w][0], pk, g0);
                        ACC_FMA(acc[w][1], pk, g1);
                        ACC_FMA(acc[w][2], pk, g2);
                        ACC_FMA(acc[w][3], pk, g3);
                    }
                }
            }
        }
        __syncthreads(); // keep the block's waves phase-aligned (alignment is soft chip-wide)
    }

    // ---- store ----
#pragma unroll
    for (int w = 0; w < 2; ++w) {
        bool v = w ? valid1 : valid0;
        if (v) {
#pragma unroll
            for (int q = 0; q < 4; ++q)
                __builtin_nontemporal_store(acc[w][q], out + (pt0 + w) * 4 + q);
        }
    }
}

extern "C" void kernel_launch(void* const* d_in, const int* in_sizes, int n_in,
                              void* d_out, int out_size, void* d_ws, size_t ws_size,
                              hipStream_t stream) {
    const float* x  = (const float*)d_in[0];
    const v4f*   f0 = (const v4f*)d_in[1];
    const v4f*   f1 = (const v4f*)d_in[2];
    const v4f*   f2 = (const v4f*)d_in[3];
    const int*   i0 = (const int*)d_in[4];
    const int*   i1 = (const int*)d_in[5];
    const int*   i2 = (const int*)d_in[6];
    v4f* out = (v4f*)d_out;

    int n_pts = in_sizes[0] / 3;

    // Bucket geometry from the table size: ~8 phases, each a 16 MB/level slice.
    long long rows = (long long)in_sizes[1] / 16; // (N_CORNERS + 1) feature rows
    int shift = 0;
    while (((rows - 1) >> shift) >= 8) ++shift;
    int nphase = (int)(((rows - 1) >> shift) + 1);

    long long threads = (n_pts + 1) / 2; // 2 points per thread
    int block = 256;
    int grid = (int)((threads + block - 1) / block);

    FeatureOctree_74749610820348_kernel<<<grid, block, 0, stream>>>(
        x, f0, f1, f2, i0, i1, i2, out, n_pts, shift, nphase);
}

// Round 4
// 1857.315 us; speedup vs baseline: 1.1295x; 1.1295x over previous
//
#include <hip/hip_runtime.h>

// FeatureOctree, bucket-phased gather — spill-free retry of R3.
//
// R3's probe was confounded: __launch_bounds__(256,4) capped VGPRs at 128,
// the compiler spilled the per-thread state (WRITE_SIZE 62.5e3 -> 730e3 KB =
// scratch traffic), so the LLC-retention hypothesis got no clean read.
//
// This version: 1 point per thread, ~60 live values (24 idx + 16 acc + 18
// interp coeffs) -> ~90 VGPR, no spill, no min-waves clamp. Phase sweep over
// H=8 index buckets; in phase h the chip gathers only from a 48 MB slice
// (3 levels x 16 MB). ~2.7 block generations in flight x 48 MB = ~144 MB
// combined working set < 256 MB LLC, so approximate phase alignment holds.
//
// Known cost: each corner's `if (bucket==h)` body issues for ~every wave
// every phase (exec-masked) -> gather-section instruction count ~8x;
// VALUBusy predicted ~20-30% (headroom: pipe is at 5%).
//
// Pre-committed read: WRITE back at ~62.5e3 KB => clean probe. Then
// FETCH < 1.0e6 KB = retention works; FETCH >= 1.4e6 KB = hypothesis
// refuted, R2 (518 us) is the random-64B roofline.

typedef float v4f __attribute__((ext_vector_type(4)));
typedef int   v4i __attribute__((ext_vector_type(4)));

#define ACC_FMA(A, PK, G)                      \
    do {                                       \
        (A).x = fmaf((PK), (G).x, (A).x);      \
        (A).y = fmaf((PK), (G).y, (A).y);      \
        (A).z = fmaf((PK), (G).z, (A).z);      \
        (A).w = fmaf((PK), (G).w, (A).w);      \
    } while (0)

__global__ __launch_bounds__(256) void FeatureOctree_74749610820348_kernel(
    const float* __restrict__ x,
    const v4f* __restrict__ f0,
    const v4f* __restrict__ f1,
    const v4f* __restrict__ f2,
    const int* __restrict__ i0,
    const int* __restrict__ i1,
    const int* __restrict__ i2,
    v4f* __restrict__ out,
    int n_pts, int shift, int nphase)
{
    long long tid = (long long)blockIdx.x * blockDim.x + threadIdx.x;
    bool valid = (tid < n_pts);
    long long pt = valid ? tid : (long long)(n_pts - 1); // clamp: keep all
                                                         // threads alive for
                                                         // __syncthreads
    // ---- idx rows -> 24 registers (all indices static after unroll) ----
    int id[3][8];
    const int* __restrict__ itab[3] = { i0, i1, i2 };
#pragma unroll
    for (int lv = 0; lv < 3; ++lv) {
        const v4i* iv = (const v4i*)(itab[lv] + pt * 8);
        v4i ia = __builtin_nontemporal_load(iv);
        v4i ib = __builtin_nontemporal_load(iv + 1);
        id[lv][0] = ia.x; id[lv][1] = ia.y; id[lv][2] = ia.z; id[lv][3] = ia.w;
        id[lv][4] = ib.x; id[lv][5] = ib.y; id[lv][6] = ib.z; id[lv][7] = ib.w;
    }

    // ---- interp coeffs per level, hoisted (18 registers) ----
    float xv = __builtin_nontemporal_load(x + pt * 3 + 0);
    float yv = __builtin_nontemporal_load(x + pt * 3 + 1);
    float zv = __builtin_nontemporal_load(x + pt * 3 + 2);
    float bx = xv * 0.5f + 0.5f;
    float by = yv * 0.5f + 0.5f;
    float bz = zv * 0.5f + 0.5f;

    float tx[3], ty[3], tz[3], ux[3], uy[3], uz[3];
#pragma unroll
    for (int lv = 0; lv < 3; ++lv) {
        const float scl = (lv == 0) ? 4096.0f : (lv == 1) ? 2048.0f : 1024.0f;
        float cx = scl * bx, cy = scl * by, cz = scl * bz;
        float dx = cx - floorf(cx);
        float dy = cy - floorf(cy);
        float dz = cz - floorf(cz);
        tx[lv] = dx * dx * (3.0f - 2.0f * dx);
        ty[lv] = dy * dy * (3.0f - 2.0f * dy);
        tz[lv] = dz * dz * (3.0f - 2.0f * dz);
        ux[lv] = 1.0f - tx[lv];
        uy[lv] = 1.0f - ty[lv];
        uz[lv] = 1.0f - tz[lv];
    }

    v4f acc[4];
#pragma unroll
    for (int q = 0; q < 4; ++q) acc[q] = (v4f){0.f, 0.f, 0.f, 0.f};

    const v4f* __restrict__ ftab[3] = { f0, f1, f2 };

    // ---- bucket-phase sweep ----
    for (int h = 0; h < nphase; ++h) {
#pragma unroll
        for (int lv = 0; lv < 3; ++lv) {
#pragma unroll
            for (int k = 0; k < 8; ++k) {
                int idk = id[lv][k];
                if ((idk >> shift) == h) {
                    float pk = ((k & 4) ? tx[lv] : ux[lv])
                             * ((k & 2) ? ty[lv] : uy[lv])
                             * ((k & 1) ? tz[lv] : uz[lv]);
                    const v4f* row = ftab[lv] + (long long)idk * 4;
                    v4f g0 = row[0];
                    v4f g1 = row[1];
                    v4f g2 = row[2];
                    v4f g3 = row[3];
                    ACC_FMA(acc[0], pk, g0);
                    ACC_FMA(acc[1], pk, g1);
                    ACC_FMA(acc[2], pk, g2);
                    ACC_FMA(acc[3], pk, g3);
                }
            }
        }
        __syncthreads(); // phase alignment within block (soft chip-wide)
    }

    // ---- store ----
    if (valid) {
#pragma unroll
        for (int q = 0; q < 4; ++q)
            __builtin_nontemporal_store(acc[q], out + pt * 4 + q);
    }
}

extern "C" void kernel_launch(void* const* d_in, const int* in_sizes, int n_in,
                              void* d_out, int out_size, void* d_ws, size_t ws_size,
                              hipStream_t stream) {
    const float* x  = (const float*)d_in[0];
    const v4f*   f0 = (const v4f*)d_in[1];
    const v4f*   f1 = (const v4f*)d_in[2];
    const v4f*   f2 = (const v4f*)d_in[3];
    const int*   i0 = (const int*)d_in[4];
    const int*   i1 = (const int*)d_in[5];
    const int*   i2 = (const int*)d_in[6];
    v4f* out = (v4f*)d_out;

    int n_pts = in_sizes[0] / 3;

    // Bucket geometry from the table size: H=8 phases, 16 MB/level slices.
    long long rows = (long long)in_sizes[1] / 16; // (N_CORNERS + 1) rows
    int shift = 0;
    while (((rows - 1) >> shift) >= 8) ++shift;
    int nphase = (int)(((rows - 1) >> shift) + 1);

    int block = 256;
    int grid = (int)(((long long)n_pts + block - 1) / block);

    FeatureOctree_74749610820348_kernel<<<grid, block, 0, stream>>>(
        x, f0, f1, f2, i0, i1, i2, out, n_pts, shift, nphase);
}